// Round 8
// baseline (197.608 us; speedup 1.0000x reference)
//
#include <hip/hip_runtime.h>
#include <math.h>

typedef __attribute__((ext_vector_type(8))) short bf16x8;
typedef __attribute__((ext_vector_type(8))) unsigned short u16x8;
typedef __attribute__((ext_vector_type(4))) unsigned short u16x4;
typedef __attribute__((ext_vector_type(4))) float f32x4;
typedef unsigned short u16;

__device__ __forceinline__ u16 f2bf(float f) {
  unsigned u = __builtin_bit_cast(unsigned, f);
  return (u16)((u + 0x7FFFu + ((u >> 16) & 1u)) >> 16);
}

__device__ __forceinline__ void gload16(const u16* g, u16* l) {
  __builtin_amdgcn_global_load_lds((const __attribute__((address_space(1))) void*)g,
                                   (__attribute__((address_space(3))) void*)l, 16, 0, 0);
}

__device__ __forceinline__ void sbar() {
  __builtin_amdgcn_sched_barrier(0);
  __builtin_amdgcn_s_barrier();
  __builtin_amdgcn_sched_barrier(0);
}

#define VMWAIT(n) asm volatile("s_waitcnt vmcnt(" #n ")" ::: "memory")
#define MFMA16(a, b, c) __builtin_amdgcn_mfma_f32_16x16x32_bf16((a), (b), (c), 0, 0, 0)

__device__ __forceinline__ float decay_of(float d) {
  return 1e-12f + 0.5f + 0.5f / (1.0f + expf(-d));
}

// Packed-B layout (per GEMM): pack[bn(128 N-rows)][ktile(64K)][n16(8)][kh(2)][kc(4)][row(16)][8elem]
// Fragment (bn, t, n16, kh) is 1 KB, lane l reads 16B at +l*16 (fully coalesced).
__device__ __forceinline__ size_t pack_idx(int nrow, int k) {
  // returns u16x8-unit index for (N-row nrow, K-offset k..k+7), NT=32 ktiles
  const int bn = nrow >> 7, n16 = (nrow >> 4) & 7, row = nrow & 15;
  const int kt = k >> 6, kh = (k >> 5) & 1, kc = (k >> 3) & 3;
  return ((((size_t)(bn * 32 + kt) * 8 + n16) * 2 + kh) * 4 + kc) * 16 + row;
}

// ---------------- prep: 2x f32 -> bf16 (w1, w2 fused) ----------------
__global__ __launch_bounds__(256) void cvt2_kernel(const float* __restrict__ a,
                                                   const float* __restrict__ b,
                                                   u16* __restrict__ out) {
  const int i = blockIdx.x * 256 + threadIdx.x;   // i < 2 * 1048576 (float4 units)
  const float* src = (i < 1048576) ? a : b;
  const int j = (i < 1048576) ? i : i - 1048576;
  const float4 v = ((const float4*)src)[j];
  u16x4 o = { f2bf(v.x), f2bf(v.y), f2bf(v.z), f2bf(v.w) };
  ((u16x4*)out)[i] = o;
}

// ---------------- prep: audio f32 [w][j] -> packed bf16 ----------------
__global__ __launch_bounds__(256) void audio_pack_kernel(const float* __restrict__ audio,
                                                         u16* __restrict__ pack) {
  const int gid = blockIdx.x * 256 + threadIdx.x;  // 524288
  const int j = (gid & 255) * 8;
  const int wv = gid >> 8;
  const float4 v0 = *(const float4*)(audio + (size_t)wv * 2048 + j);
  const float4 v1 = *(const float4*)(audio + (size_t)wv * 2048 + j + 4);
  u16x8 o = { f2bf(v0.x), f2bf(v0.y), f2bf(v0.z), f2bf(v0.w),
              f2bf(v1.x), f2bf(v1.y), f2bf(v1.z), f2bf(v1.w) };
  *(u16x8*)(pack + pack_idx(wv, j) * 8) = o;
}

// ---------------- prep: relu(cp) -> packed-B bf16 (B of GEMM1, N-row = t) ----------------
__global__ __launch_bounds__(256) void relu_t_kernel(const float* __restrict__ cp,
                                                     u16* __restrict__ x0p) {
  const int cb = blockIdx.x & 31;
  const int tb = blockIdx.x >> 5;
  __shared__ __attribute__((aligned(16))) float tile[64][65];
  const int tid = threadIdx.x;
  const int r0 = tid >> 4, i4 = (tid & 15) * 4;
  #pragma unroll
  for (int rr = 0; rr < 64; rr += 16) {
    const float4 v = *(const float4*)(cp + (size_t)(cb * 64 + r0 + rr) * 4096 + tb * 64 + i4);
    tile[r0 + rr][i4 + 0] = fmaxf(v.x, 0.f);
    tile[r0 + rr][i4 + 1] = fmaxf(v.y, 0.f);
    tile[r0 + rr][i4 + 2] = fmaxf(v.z, 0.f);
    tile[r0 + rr][i4 + 3] = fmaxf(v.w, 0.f);
  }
  __syncthreads();
  #pragma unroll
  for (int it = 0; it < 2; ++it) {
    const int chunk = it * 256 + tid;
    const int i = chunk >> 3, rp = (chunk & 7) * 8;
    u16x8 o;
    #pragma unroll
    for (int q = 0; q < 8; ++q) o[q] = f2bf(tile[rp + q][i]);
    *(u16x8*)(x0p + pack_idx(tb * 64 + i, cb * 64 + rp) * 8) = o;
  }
}

// ---------------- IIR blocked scan ----------------
__global__ __launch_bounds__(128) void iir_partial_kernel(const float* __restrict__ x,
                                                          const float* __restrict__ decays,
                                                          float* __restrict__ L) {
  const int tid = threadIdx.x;
  const int cb = blockIdx.x & 15;
  const int ck = blockIdx.x >> 4;
  const int c0 = cb * 128, t0 = ck * 64;
  __shared__ __attribute__((aligned(16))) float xs[128][65];
  const float dd = decay_of(decays[c0 + tid]);
  #pragma unroll
  for (int it = 0; it < 16; ++it) {
    const int idx = it * 128 + tid;
    const int r = idx >> 4, iv = (idx & 15) * 4;
    const float4 v = *(const float4*)(x + (size_t)(c0 + r) * 4096 + t0 + iv);
    xs[r][iv + 0] = v.x; xs[r][iv + 1] = v.y; xs[r][iv + 2] = v.z; xs[r][iv + 3] = v.w;
  }
  __syncthreads();
  float yv = 0.0f;
  #pragma unroll
  for (int i = 0; i < 64; ++i) yv = dd * (xs[tid][i] + yv);
  L[ck * 2048 + c0 + tid] = yv;
}

__global__ __launch_bounds__(128) void iir_carry_kernel(const float* __restrict__ L,
                                                        const float* __restrict__ decays,
                                                        float* __restrict__ Cin) {
  const int c = blockIdx.x * 128 + threadIdx.x;
  const float dd = decay_of(decays[c]);
  float A = dd;
  #pragma unroll
  for (int p = 0; p < 6; ++p) A = A * A;   // dd^64
  float carry = 0.0f;
  for (int j = 0; j < 64; ++j) {
    Cin[j * 2048 + c] = carry;
    carry = L[j * 2048 + c] + A * carry;
  }
}

// writes y packed-B (B of GEMM2, N-row = t)
__global__ __launch_bounds__(128) void iir_apply_kernel(const float* __restrict__ x,
                                                        const float* __restrict__ decays,
                                                        const float* __restrict__ Cin,
                                                        u16* __restrict__ yp) {
  const int tid = threadIdx.x;
  const int cb = blockIdx.x & 15;
  const int ck = blockIdx.x >> 4;
  const int c0 = cb * 128, t0 = ck * 64;
  __shared__ __attribute__((aligned(16))) float xs[128][65];
  __shared__ __attribute__((aligned(16))) u16 ys[64][136];
  const float dd = decay_of(decays[c0 + tid]);
  const float carry = Cin[ck * 2048 + c0 + tid];
  #pragma unroll
  for (int it = 0; it < 16; ++it) {
    const int idx = it * 128 + tid;
    const int r = idx >> 4, iv = (idx & 15) * 4;
    const float4 v = *(const float4*)(x + (size_t)(c0 + r) * 4096 + t0 + iv);
    xs[r][iv + 0] = v.x; xs[r][iv + 1] = v.y; xs[r][iv + 2] = v.z; xs[r][iv + 3] = v.w;
  }
  __syncthreads();
  float yv = carry;
  #pragma unroll
  for (int i = 0; i < 64; ++i) {
    yv = dd * (xs[tid][i] + yv);
    ys[i][tid] = f2bf(yv);
  }
  __syncthreads();
  #pragma unroll
  for (int it = 0; it < 8; ++it) {
    const int chunk = it * 128 + tid;
    const int i = chunk >> 4, cpv = (chunk & 15) * 8;
    u16x8 v = *(const u16x8*)&ys[i][cpv];
    *(u16x8*)(yp + pack_idx(t0 + i, c0 + cpv) * 8) = v;
  }
}

// ---------------- GEMM: 128x128, BK=64; A LDS-dbuf (swizzled), B packed global->reg ----------------
// C[M][N] = A[M][K] @ B^T via packed B. 256 thr = 4 waves (2M x 2N), per-wave 64x64.
// Per tile: issue B(t+1)->regs [8]; vmcnt(12) [B(t) landed]; ds_read A [8]; 32 MFMA;
// vmcnt(8) [A-stage(t+1) landed]; barrier; stage A(t+2) [4 gload_lds]. No drain in loop.
template <int MODE>
__global__ __launch_bounds__(256, 2) void gemm_bg_kernel(
    const u16* __restrict__ A, const u16* __restrict__ Bp, float* __restrict__ C,
    int N, int K, int xlogn,
    const float* __restrict__ orig, const float* __restrict__ gains,
    u16* __restrict__ CbT) {
  __shared__ __attribute__((aligned(16))) u16 Asb[2][128 * 64];  // 32 KB total
  const int tid = threadIdx.x;
  const int l = tid & 63, w = tid >> 6;
  const int xc = blockIdx.x & 7, rblk = blockIdx.x >> 3;
  const int xn = xc & ((1 << xlogn) - 1), xm = xc >> xlogn;
  const int bm = xm * 8 + (rblk >> 3);
  const int bn = xn * 8 + (rblk & 7);
  const int nt = K >> 6;   // 32 (even)

  // A staging geometry (swizzled; LDS[r][c] = G[r][c ^ (r&7)])
  const int cs = (l & 7) ^ (l >> 3);
  const int rsub = l >> 3;
  const u16* aS[4]; int tO[4];
  #pragma unroll
  for (int u = 0; u < 4; ++u) {
    const int rg = (u * 4 + w) * 8 + rsub;
    aS[u] = A + (size_t)(bm * 128 + rg) * K + cs * 8;
    tO[u] = (u * 4 + w) * 512;
  }

#define STAGEA(buf, tt) do {                                               \
    const long so_ = (long)(tt) * 64;                                      \
    gload16(aS[0] + so_, (buf) + tO[0]); gload16(aS[1] + so_, (buf) + tO[1]); \
    gload16(aS[2] + so_, (buf) + tO[2]); gload16(aS[3] + so_, (buf) + tO[3]); \
  } while (0)

  const int wr = w >> 1, wc = w & 1;
  const int rA0 = wr * 64 + (l & 15);
  const int jk0 = (l >> 4) ^ (l & 7);
  const int jk1 = ((l >> 4) + 4) ^ (l & 7);

  // B packed: frag (t, ni, kh) at bBase + t*8192 + ni*1024 + kh*512 (u16 units)
  const u16* bBase = Bp + ((size_t)bn * nt * 8 + wc * 4) * 1024 + (size_t)l * 8;

#define LOADB(dst, tt) do {                                                \
    const u16* bp_ = bBase + (size_t)(tt) * 8192;                          \
    dst[0][0] = *(const bf16x8*)(bp_ +    0); dst[0][1] = *(const bf16x8*)(bp_ +  512); \
    dst[1][0] = *(const bf16x8*)(bp_ + 1024); dst[1][1] = *(const bf16x8*)(bp_ + 1536); \
    dst[2][0] = *(const bf16x8*)(bp_ + 2048); dst[2][1] = *(const bf16x8*)(bp_ + 2560); \
    dst[3][0] = *(const bf16x8*)(bp_ + 3072); dst[3][1] = *(const bf16x8*)(bp_ + 3584); \
  } while (0)

#define COMPUTE(Ab, bfr) do {                                              \
    bf16x8 af[4][2];                                                       \
    _Pragma("unroll")                                                      \
    for (int mi = 0; mi < 4; ++mi) {                                       \
      af[mi][0] = *(const bf16x8*)((Ab) + (rA0 + mi * 16) * 64 + jk0 * 8); \
      af[mi][1] = *(const bf16x8*)((Ab) + (rA0 + mi * 16) * 64 + jk1 * 8); \
    }                                                                      \
    __builtin_amdgcn_s_setprio(1);                                         \
    _Pragma("unroll")                                                      \
    for (int mi = 0; mi < 4; ++mi)                                         \
      _Pragma("unroll")                                                    \
      for (int ni = 0; ni < 4; ++ni)                                       \
        acc[mi][ni] = MFMA16(af[mi][0], bfr[ni][0], acc[mi][ni]);          \
    _Pragma("unroll")                                                      \
    for (int mi = 0; mi < 4; ++mi)                                         \
      _Pragma("unroll")                                                    \
      for (int ni = 0; ni < 4; ++ni)                                       \
        acc[mi][ni] = MFMA16(af[mi][1], bfr[ni][1], acc[mi][ni]);          \
    __builtin_amdgcn_s_setprio(0);                                         \
  } while (0)

  f32x4 acc[4][4];
  #pragma unroll
  for (int i = 0; i < 4; ++i)
    #pragma unroll
    for (int j = 0; j < 4; ++j) acc[i][j] = (f32x4){0.f, 0.f, 0.f, 0.f};

  bf16x8 bfE[4][2], bfO[4][2];

  // prologue: A(0), B(0), A(1); drain A(0); barrier.
  STAGEA((u16*)Asb[0], 0);       // 4
  LOADB(bfE, 0);                 // 8
  STAGEA((u16*)Asb[1], 1);       // 4
  VMWAIT(12);                    // A(0) landed; [B(0) 8, A(1) 4] in flight
  sbar();

  for (int t = 0; t < nt; t += 2) {
    // ---- even tile t: LDS buf0, bfE ----
    if (t + 1 < nt) LOADB(bfO, t + 1);
    if (t < nt - 2) { VMWAIT(12); } else { VMWAIT(0); }  // B(t) landed
    COMPUTE((const u16*)Asb[0], bfE);
    if (t < nt - 2) { VMWAIT(8); } else { VMWAIT(0); }   // A-stage(t+1) landed
    sbar();
    if (t + 2 < nt) STAGEA((u16*)Asb[0], t + 2);
    // ---- odd tile t+1: LDS buf1, bfO ----
    if (t + 2 < nt) LOADB(bfE, t + 2);
    if (t + 1 < nt - 2) { VMWAIT(12); } else { VMWAIT(0); }
    COMPUTE((const u16*)Asb[1], bfO);
    if (t + 1 < nt - 2) { VMWAIT(8); } else { VMWAIT(0); }
    sbar();
    if (t + 3 < nt) STAGEA((u16*)Asb[1], t + 3);
  }
#undef STAGEA
#undef LOADB
#undef COMPUTE

  // ---------------- epilogue ----------------
  const int rb = bm * 128 + wr * 64 + ((l >> 4) * 4);
  const int cb = bn * 128 + wc * 64 + (l & 15);
  #pragma unroll
  for (int mi = 0; mi < 4; ++mi) {
    const int row0 = rb + mi * 16;
    float gv[4] = {0.f, 0.f, 0.f, 0.f};
    if (MODE == 1) {
      #pragma unroll
      for (int j = 0; j < 4; ++j) gv[j] = 5.0f / (1.0f + expf(-gains[row0 + j]));
    }
    #pragma unroll
    for (int ni = 0; ni < 4; ++ni) {
      const int col = cb + ni * 16;
      f32x4 v = acc[mi][ni];
      if (MODE == 1) {
        float cpv[4];
        #pragma unroll
        for (int j = 0; j < 4; ++j) {
          float t = v[j] + orig[(size_t)(row0 + j) * N + col];
          cpv[j] = tanhf(t * gv[j]);
          C[(size_t)(row0 + j) * N + col] = cpv[j];
        }
        u16x4 o = { f2bf(cpv[0]), f2bf(cpv[1]), f2bf(cpv[2]), f2bf(cpv[3]) };
        *(u16x4*)(CbT + (size_t)col * 2048 + row0) = o;
      } else {
        #pragma unroll
        for (int j = 0; j < 4; ++j)
          C[(size_t)(row0 + j) * N + col] = v[j];
      }
    }
  }
}

extern "C" void kernel_launch(void* const* d_in, const int* in_sizes, int n_in,
                              void* d_out, int out_size, void* d_ws, size_t ws_size,
                              hipStream_t stream) {
  const float* cp     = (const float*)d_in[0];
  const float* w1     = (const float*)d_in[1];
  const float* w2     = (const float*)d_in[2];
  const float* audio  = (const float*)d_in[3];
  const float* decays = (const float*)d_in[4];
  const float* gains  = (const float*)d_in[5];

  float* out0 = (float*)d_out;                   // audio_out: [t][w] flat
  float* out1 = out0 + (size_t)2048 * 4096;      // cp_out: [c][t]

  char* ws = (char*)d_ws;
  u16*   w1b    = (u16*)(ws);                    //  8 MB (w1 + w2 = 16 MB)
  u16*   w2b    = (u16*)(ws + 8388608);
  u16*   audp   = (u16*)(ws + 16777216);         //  8 MB packed audio
  float* orig   = (float*)(ws + 25165824);       // 32 MB
  u16*   yp     = (u16*)(ws + 58720256);         // 16 MB packed y
  u16*   x0p    = (u16*)(ws + 75497472);         // 16 MB packed relu(cp)
  u16*   cpbT   = x0p;                           // reuse after GEMM1 (row-major [t][c])
  float* Lbuf   = (float*)(ws + 75497472);       // overlap (dead between GEMM1/GEMM2)
  float* Cin    = (float*)(ws + 75497472 + 524288);

  cvt2_kernel<<<8192, 256, 0, stream>>>(w1, w2, w1b);
  audio_pack_kernel<<<2048, 256, 0, stream>>>(audio, audp);
  relu_t_kernel<<<2048, 256, 0, stream>>>(cp, x0p);

  // x = w1 @ relu(cp) -> orig[2048][4096]   (16bm x 32bn; XCD grid 2x4)
  gemm_bg_kernel<0><<<512, 256, 0, stream>>>(w1b, x0p, orig, 4096, 2048, 2,
                                             nullptr, nullptr, nullptr);
  // y = IIR(orig) -> yp packed
  iir_partial_kernel<<<1024, 128, 0, stream>>>(orig, decays, Lbuf);
  iir_carry_kernel<<<16, 128, 0, stream>>>(Lbuf, decays, Cin);
  iir_apply_kernel<<<1024, 128, 0, stream>>>(orig, decays, Cin, yp);
  // x2 = w2 @ y + orig; cp_out = tanh(x2*g) -> out1 f32, cpbT[t][c] bf16
  gemm_bg_kernel<1><<<512, 256, 0, stream>>>(w2b, yp, out1, 4096, 2048, 2,
                                             orig, gains, cpbT);
  // audio_out[t][w] = cpbT @ audio^T   (32bm x 16bn; XCD grid 4x2)
  gemm_bg_kernel<0><<<512, 256, 0, stream>>>(cpbT, audp, out0, 2048, 2048, 1,
                                             nullptr, nullptr, nullptr);
}